// Round 7
// baseline (172.091 us; speedup 1.0000x reference)
//
#include <hip/hip_runtime.h>
#include <cstdint>
#include <cstddef>

typedef __bf16 bf16_t;
typedef __bf16 bf16x8 __attribute__((ext_vector_type(8)));
typedef __bf16 bf16x4 __attribute__((ext_vector_type(4)));
typedef float f32x4 __attribute__((ext_vector_type(4)));

#define N_SEQ 2048
#define BATCH 2
#define EMB   1024
#define HID   1024
#define NHEAD 16
#define HDIM  64
#define NBROW (N_SEQ * BATCH)   /* 4096 GEMM rows (n*B+b) */
#define ATT_SCALE2 (0.03125f * 1.44269504f)  /* 1/sqrt(1024) * log2(e) */

#define EXP2F(x) __builtin_amdgcn_exp2f(x)   /* __exp2f collides with glibc macro */

static __device__ __forceinline__ void async_copy16(const bf16_t* g, bf16_t* l) {
  __builtin_amdgcn_global_load_lds((const __attribute__((address_space(1))) void*)g,
                                   (__attribute__((address_space(3))) void*)l,
                                   16, 0, 0);
}

// ---------------- fused prep: convert x + transpose both weights -----------
__global__ __launch_bounds__(256) void prep_kernel(
    const float* __restrict__ x, const float* __restrict__ Wp,
    const float* __restrict__ Wo, bf16_t* __restrict__ Xb,
    bf16_t* __restrict__ Wpt, bf16_t* __restrict__ Wot) {
  int bid = blockIdx.x;
  if (bid < 4096) {
    int i = (bid * 256 + threadIdx.x) * 4;
    float4 v = *(const float4*)(x + i);
    bf16x4 o;
    o[0] = (bf16_t)v.x; o[1] = (bf16_t)v.y; o[2] = (bf16_t)v.z; o[3] = (bf16_t)v.w;
    *(bf16x4*)(Xb + i) = o;
    return;
  }
  __shared__ float tile[32][33];
  const float* in; bf16_t* out; int R, C, bx;
  if (bid < 4096 + 3072) { bx = bid - 4096; in = Wp; out = Wpt; R = 1024; C = 3072; }
  else                   { bx = bid - 7168; in = Wo; out = Wot; R = 1024; C = 1024; }
  int gx = C / 32;
  int bc = (bx % gx) * 32, br = (bx / gx) * 32;
  int tx = threadIdx.x & 31, ty = threadIdx.x >> 5;   // 32 x 8
  #pragma unroll
  for (int i = 0; i < 32; i += 8)
    tile[ty + i][tx] = in[(size_t)(br + ty + i) * C + bc + tx];
  __syncthreads();
  #pragma unroll
  for (int i = 0; i < 32; i += 8)
    out[(size_t)(bc + ty + i) * R + br + tx] = (bf16_t)tile[tx][ty + i];
}

// ---------------- pipelined GEMM: C = A * Bt^T + bias ----------------------
// Round-1 verified version (BM=128, BN=128).
template <int BM, int BN, bool OUT_BF16, bool SCALEQ, bool WRITE_VT>
__global__ __launch_bounds__(256) void gemm_bt_kernel(
    const bf16_t* __restrict__ A, const bf16_t* __restrict__ Bt,
    const float* __restrict__ bias, void* __restrict__ Cout,
    bf16_t* __restrict__ Vt, int M, int Nn, int K) {
  constexpr int BK = 64;
  constexpr int MT = BM / 32;
  constexpr int NT = BN / 32;
  constexpr int CA = BM / 32;
  constexpr int CB = BN / 32;
  constexpr int ASZ = BM * BK;
  constexpr int BSZ = BN * BK;
  __shared__ __align__(16) bf16_t smem[2 * ASZ + 2 * BSZ];
  bf16_t* const Asb = smem;
  bf16_t* const Bsb = smem + 2 * ASZ;
  int tid = threadIdx.x;
  int wave = tid >> 6, lane = tid & 63;
  int c = lane & 15, quad = lane >> 4;
  int bm = blockIdx.x * BM;
  int bn = blockIdx.y * BN;
  int wm = (wave & 1) * (BM / 2), wn = (wave >> 1) * (BN / 2);
  f32x4 acc[MT][NT] = {};

  const bf16_t* agp[CA]; int alo[CA];
  const bf16_t* bgp[CB]; int blo[CB];
  #pragma unroll
  for (int i = 0; i < CA; ++i) {
    int p = i * 256 + tid;
    int row = p >> 3, ko = (p & 7) ^ (row & 7);
    agp[i] = A + (size_t)(bm + row) * K + ko * 8;
    alo[i] = (i * 256 + wave * 64) * 8;
  }
  #pragma unroll
  for (int i = 0; i < CB; ++i) {
    int p = i * 256 + tid;
    int row = p >> 3, ko = (p & 7) ^ (row & 7);
    bgp[i] = Bt + (size_t)(bn + row) * K + ko * 8;
    blo[i] = (i * 256 + wave * 64) * 8;
  }

  #pragma unroll
  for (int i = 0; i < CA; ++i) async_copy16(agp[i], Asb + alo[i]);
  #pragma unroll
  for (int i = 0; i < CB; ++i) async_copy16(bgp[i], Bsb + blo[i]);

  int nkb = K / BK;
  for (int ki = 0; ki < nkb; ++ki) {
    __syncthreads();
    if (ki + 1 < nkb) {
      int kb = (ki + 1) * BK;
      bf16_t* an = Asb + ((ki + 1) & 1) * ASZ;
      bf16_t* bnx = Bsb + ((ki + 1) & 1) * BSZ;
      #pragma unroll
      for (int i = 0; i < CA; ++i) async_copy16(agp[i] + kb, an + alo[i]);
      #pragma unroll
      for (int i = 0; i < CB; ++i) async_copy16(bgp[i] + kb, bnx + blo[i]);
    }
    const bf16_t* as = Asb + (ki & 1) * ASZ;
    const bf16_t* bs = Bsb + (ki & 1) * BSZ;
    #pragma unroll
    for (int kk = 0; kk < 2; ++kk) {
      bf16x8 af[MT], bf[NT];
      #pragma unroll
      for (int mt = 0; mt < MT; ++mt) {
        int row = wm + mt * 16 + c;
        int slot = (kk * 4 + quad) ^ (row & 7);
        af[mt] = *(const bf16x8*)(as + (size_t)(row * 8 + slot) * 8);
      }
      #pragma unroll
      for (int nt = 0; nt < NT; ++nt) {
        int row = wn + nt * 16 + c;
        int slot = (kk * 4 + quad) ^ (row & 7);
        bf[nt] = *(const bf16x8*)(bs + (size_t)(row * 8 + slot) * 8);
      }
      #pragma unroll
      for (int mt = 0; mt < MT; ++mt)
        #pragma unroll
        for (int nt = 0; nt < NT; ++nt)
          acc[mt][nt] = __builtin_amdgcn_mfma_f32_16x16x32_bf16(
              af[mt], bf[nt], acc[mt][nt], 0, 0, 0);
    }
  }

  bool do_vt = WRITE_VT && (bn >= 2 * HID);
  bf16_t* tb = smem;
  if (do_vt) __syncthreads();

  #pragma unroll
  for (int nt = 0; nt < NT; ++nt) {
    int col = bn + wn + nt * 16 + c;
    float bv = bias[col];
    float sc = (SCALEQ && col < HID) ? ATT_SCALE2 : 1.0f;
    #pragma unroll
    for (int mt = 0; mt < MT; ++mt) {
      #pragma unroll
      for (int r = 0; r < 4; ++r) {
        int loc = wm + mt * 16 + quad * 4 + r;
        int row = bm + loc;
        float v = (acc[mt][nt][r] + bv) * sc;
        if (OUT_BF16)
          ((bf16_t*)Cout)[(size_t)row * Nn + col] = (bf16_t)v;
        else
          ((float*)Cout)[(size_t)row * Nn + col] = v;
        if (do_vt) {
          int dg = wn + nt * 16 + c;
          int hh = dg >> 6, dl = dg & 63;
          tb[((loc & 1) * 2 + hh) * 4608 + dl * 72 + (loc >> 1)] = (bf16_t)v;
        }
      }
    }
  }

  if (do_vt) {
    __syncthreads();
    int h0 = (bn - 2 * HID) >> 6;
    int n2 = (tid & 7) * 8;
    #pragma unroll
    for (int i = 0; i < 2; ++i) {
      #pragma unroll
      for (int hh = 0; hh < 2; ++hh) {
        #pragma unroll
        for (int k = 0; k < 2; ++k) {
          int d = (tid >> 3) + k * 32;
          bf16x8 vv = *(const bf16x8*)(tb + ((i * 2 + hh) * 4608) + d * 72 + n2);
          *(bf16x8*)(Vt + (size_t)((i * 16 + h0 + hh) * HDIM + d) * N_SEQ + bm / 2 + n2) = vv;
        }
      }
    }
  }
}

// ---------------- flash attention: KVBLK=128 (halved barrier count) --------
// R1 16x16 structure with j-tiles of 128: max serialized iters/block 32 -> 16.
// Ks[2][128][64] (rows j, swizzled octets), Vs[2][64][128] (rows d, swizzled
// j-octets), Ps per-wave 16x64 reused for the two j-halves (in-order per-wave
// DS ops make the WAR safe; compiler fence stops reordering).
// Diagonal tile: skip fully-masked j-subtiles (mt>wave) and, for waves 0-3,
// the entire second half.
__global__ __launch_bounds__(512, 2) void flash_attn_kernel(
    const bf16_t* __restrict__ Pj, const bf16_t* __restrict__ Vt,
    bf16_t* __restrict__ AO) {
  __shared__ __align__(16) bf16_t Ks[2][128 * 64];  // 32 KB
  __shared__ __align__(16) bf16_t Vs[2][64 * 128];  // 32 KB
  __shared__ __align__(16) bf16_t Ps[8][16 * 64];   // 16 KB
  const int PJP = 3 * HID;
  int tid = threadIdx.x, wave = tid >> 6, lane = tid & 63;
  int c = lane & 15, quad = lane >> 4;
  int c7 = c & 7;
  int bid = blockIdx.x;
  int qb = (bid < 256) ? (15 - (bid >> 5)) : ((bid - 256) >> 5);
  int bh = bid & 31;
  int h = bh & 15, b = bh >> 4;
  int i0 = qb * 128;

  int i_row = i0 + wave * 16 + c;
  const bf16_t* qg = Pj + (size_t)(i_row * BATCH + b) * PJP + h * HDIM + quad * 8;
  bf16x8 qf0 = *(const bf16x8*)(qg);
  bf16x8 qf1 = *(const bf16x8*)(qg + 32);

  f32x4 o[4] = {};                   // O^T: rows d, col i=c
  float lrow = 0.f;

  // K staging: rows jr, jr+64 at octet oc ((jr+64)&7 == jr&7)
  int jr = tid >> 3, oc = tid & 7;
  int ko0 = jr * 64 + (oc ^ (jr & 7)) * 8;
  int ko1 = (jr + 64) * 64 + (oc ^ (jr & 7)) * 8;
  const bf16_t* kg = Pj + (size_t)b * PJP + HID + h * HDIM + oc * 8;
  // V staging: d rows d0, d0+32 at j-octet joct ((d0+32)&7 == d0&7)
  int d0 = tid >> 4, joct = tid & 15;
  int vo0 = d0 * 128 + (joct ^ (d0 & 7)) * 8;
  int vo1 = (d0 + 32) * 128 + (joct ^ (d0 & 7)) * 8;
  const bf16_t* vg0 = Vt + (size_t)(bh * HDIM + d0) * N_SEQ + joct * 8;
  const bf16_t* vg1 = Vt + (size_t)(bh * HDIM + d0 + 32) * N_SEQ + joct * 8;

  int njt = qb + 1;
  bf16x8 kr0 = *(const bf16x8*)(kg + (size_t)jr * BATCH * PJP);
  bf16x8 kr1 = *(const bf16x8*)(kg + (size_t)(jr + 64) * BATCH * PJP);
  bf16x8 vr0 = *(const bf16x8*)(vg0);
  bf16x8 vr1 = *(const bf16x8*)(vg1);

  for (int jt = 0; jt < njt; ++jt) {
    bf16_t* ks = Ks[jt & 1];
    bf16_t* vs = Vs[jt & 1];
    *(bf16x8*)(ks + ko0) = kr0;
    *(bf16x8*)(ks + ko1) = kr1;
    *(bf16x8*)(vs + vo0) = vr0;
    *(bf16x8*)(vs + vo1) = vr1;
    __syncthreads();
    if (jt + 1 < njt) {
      int j0n = (jt + 1) * 128;
      kr0 = *(const bf16x8*)(kg + (size_t)(j0n + jr) * BATCH * PJP);
      kr1 = *(const bf16x8*)(kg + (size_t)(j0n + jr + 64) * BATCH * PJP);
      vr0 = *(const bf16x8*)(vg0 + j0n);
      vr1 = *(const bf16x8*)(vg1 + j0n);
    }

    bool diag = (jt == qb);
    f32x4 st[8];
    #pragma unroll
    for (int mt = 0; mt < 8; ++mt) {
      if (!diag || mt <= wave) {
        const bf16_t* kr = ks + (mt * 16 + c) * 64;
        bf16x8 ka0 = *(const bf16x8*)(kr + ((quad) ^ c7) * 8);
        bf16x8 ka1 = *(const bf16x8*)(kr + ((quad + 4) ^ c7) * 8);
        f32x4 s = {};
        s = __builtin_amdgcn_mfma_f32_16x16x32_bf16(ka0, qf0, s, 0, 0, 0);
        st[mt] = __builtin_amdgcn_mfma_f32_16x16x32_bf16(ka1, qf1, s, 0, 0, 0);
      } else {
        st[mt][0] = -1e30f; st[mt][1] = -1e30f;
        st[mt][2] = -1e30f; st[mt][3] = -1e30f;
      }
    }
    if (diag) {                      // causal mask within the diagonal tile
      int il = wave * 16 + c;
      #pragma unroll
      for (int mt = 0; mt < 8; ++mt)
        #pragma unroll
        for (int r = 0; r < 4; ++r)
          if (mt * 16 + quad * 4 + r > il) st[mt][r] = -1e30f;
    }

    #pragma unroll
    for (int mt = 0; mt < 8; ++mt)
      #pragma unroll
      for (int r = 0; r < 4; ++r) {
        st[mt][r] = EXP2F(st[mt][r]);
        lrow += st[mt][r];
      }

    bf16_t* pw = Ps[wave];
    #pragma unroll
    for (int hf = 0; hf < 2; ++hf) {
      if (hf == 0 || !diag || wave >= 4) {   // half-1 all-zero for waves 0-3 on diag
        #pragma unroll
        for (int mtl = 0; mtl < 4; ++mtl) {
          f32x4 sv = st[hf * 4 + mtl];
          bf16x4 pv;
          #pragma unroll
          for (int r = 0; r < 4; ++r) pv[r] = (bf16_t)sv[r];
          int jo = mtl * 2 + (quad >> 1);
          *(bf16x4*)(pw + c * 64 + (jo ^ c7) * 8 + (quad & 1) * 4) = pv;
        }
        const bf16_t* pr = pw + c * 64;
        bf16x8 pa0 = *(const bf16x8*)(pr + ((quad) ^ c7) * 8);
        bf16x8 pa1 = *(const bf16x8*)(pr + ((quad + 4) ^ c7) * 8);
        #pragma unroll
        for (int nt = 0; nt < 4; ++nt) {
          const bf16_t* vrp = vs + (nt * 16 + c) * 128;
          bf16x8 va0 = *(const bf16x8*)(vrp + ((hf * 8 + quad) ^ c7) * 8);
          bf16x8 va1 = *(const bf16x8*)(vrp + ((hf * 8 + 4 + quad) ^ c7) * 8);
          o[nt] = __builtin_amdgcn_mfma_f32_16x16x32_bf16(va0, pa0, o[nt], 0, 0, 0);
          o[nt] = __builtin_amdgcn_mfma_f32_16x16x32_bf16(va1, pa1, o[nt], 0, 0, 0);
        }
        asm volatile("" ::: "memory");   // keep half-1 P writes after half-0 P reads
      }
    }
  }

  float lfull = lrow;
  lfull += __shfl_xor(lfull, 16);
  lfull += __shfl_xor(lfull, 32);
  float linv = 1.0f / lfull;
  int orow = (i0 + wave * 16 + c) * BATCH + b;
  #pragma unroll
  for (int nt = 0; nt < 4; ++nt) {
    bf16x4 pv;
    #pragma unroll
    for (int r = 0; r < 4; ++r) pv[r] = (bf16_t)(o[nt][r] * linv);
    *(bf16x4*)(AO + (size_t)orow * HID + h * HDIM + nt * 16 + quad * 4) = pv;
  }
}

extern "C" void kernel_launch(void* const* d_in, const int* in_sizes, int n_in,
                              void* d_out, int out_size, void* d_ws, size_t ws_size,
                              hipStream_t stream) {
  const float* x      = (const float*)d_in[0];   // [2048][2][1024]
  const float* W_proj = (const float*)d_in[1];   // [1024][3072]
  const float* b_proj = (const float*)d_in[2];   // [3072]
  const float* W_out  = (const float*)d_in[3];   // [1024][1024]
  const float* b_out  = (const float*)d_in[4];   // [1024]

  bf16_t* Xb  = (bf16_t*)d_ws;                               // 4096*1024
  bf16_t* Wpt = Xb  + (size_t)NBROW * EMB;                   // 3072*1024
  bf16_t* Wot = Wpt + (size_t)3 * HID * EMB;                 // 1024*1024
  bf16_t* Pj  = Wot + (size_t)HID * EMB;                     // 4096*3072
  bf16_t* AO  = Pj  + (size_t)NBROW * 3 * HID;               // 4096*1024
  bf16_t* Vt  = AO  + (size_t)NBROW * HID;                   // 32*64*2048

  prep_kernel<<<8192, 256, 0, stream>>>(x, W_proj, W_out, Xb, Wpt, Wot);
  gemm_bt_kernel<128, 128, true, true, true>
      <<<dim3(NBROW / 128, 3 * HID / 128), 256, 0, stream>>>(
      Xb, Wpt, b_proj, (void*)Pj, Vt, NBROW, 3 * HID, EMB);
  flash_attn_kernel<<<512, 512, 0, stream>>>(Pj, Vt, AO);
  gemm_bt_kernel<128, 128, false, false, false>
      <<<dim3(NBROW / 128, EMB / 128), 256, 0, stream>>>(
      AO, Wot, b_out, d_out, nullptr, NBROW, EMB, HID);
}

// Round 8
// 161.899 us; speedup vs baseline: 1.0629x; 1.0629x over previous
//
#include <hip/hip_runtime.h>
#include <cstdint>
#include <cstddef>

typedef __bf16 bf16_t;
typedef __bf16 bf16x8 __attribute__((ext_vector_type(8)));
typedef __bf16 bf16x4 __attribute__((ext_vector_type(4)));
typedef float f32x4 __attribute__((ext_vector_type(4)));

#define N_SEQ 2048
#define BATCH 2
#define EMB   1024
#define HID   1024
#define NHEAD 16
#define HDIM  64
#define NBROW (N_SEQ * BATCH)   /* 4096 GEMM rows (n*B+b) */
#define ATT_SCALE2 (0.03125f * 1.44269504f)  /* 1/sqrt(1024) * log2(e) */

#define EXP2F(x) __builtin_amdgcn_exp2f(x)   /* __exp2f collides with glibc macro */

static __device__ __forceinline__ void async_copy16(const bf16_t* g, bf16_t* l) {
  __builtin_amdgcn_global_load_lds((const __attribute__((address_space(1))) void*)g,
                                   (__attribute__((address_space(3))) void*)l,
                                   16, 0, 0);
}

// ---------------- fused prep: convert x + transpose both weights -----------
__global__ __launch_bounds__(256) void prep_kernel(
    const float* __restrict__ x, const float* __restrict__ Wp,
    const float* __restrict__ Wo, bf16_t* __restrict__ Xb,
    bf16_t* __restrict__ Wpt, bf16_t* __restrict__ Wot) {
  int bid = blockIdx.x;
  if (bid < 4096) {
    int i = (bid * 256 + threadIdx.x) * 4;
    float4 v = *(const float4*)(x + i);
    bf16x4 o;
    o[0] = (bf16_t)v.x; o[1] = (bf16_t)v.y; o[2] = (bf16_t)v.z; o[3] = (bf16_t)v.w;
    *(bf16x4*)(Xb + i) = o;
    return;
  }
  __shared__ float tile[32][33];
  const float* in; bf16_t* out; int R, C, bx;
  if (bid < 4096 + 3072) { bx = bid - 4096; in = Wp; out = Wpt; R = 1024; C = 3072; }
  else                   { bx = bid - 7168; in = Wo; out = Wot; R = 1024; C = 1024; }
  int gx = C / 32;
  int bc = (bx % gx) * 32, br = (bx / gx) * 32;
  int tx = threadIdx.x & 31, ty = threadIdx.x >> 5;   // 32 x 8
  #pragma unroll
  for (int i = 0; i < 32; i += 8)
    tile[ty + i][tx] = in[(size_t)(br + ty + i) * C + bc + tx];
  __syncthreads();
  #pragma unroll
  for (int i = 0; i < 32; i += 8)
    out[(size_t)(bc + ty + i) * R + br + tx] = (bf16_t)tile[tx][ty + i];
}

// ---------------- QKV GEMM: 128x128, BK=32, THREE buffers (48KB LDS) -------
// Fixes the 2-blocks/CU grid quantization of the 64KB version: 768 blocks at
// 3 blocks/CU = all co-resident, one round, no half-empty tail.
// Depth-2 prefetch with counted s_waitcnt vmcnt(4) (tile-s's 4 loads are two
// iterations old at the wait; vmcnt never drains to 0 in the main loop).
// Swizzle (4 octets/row, R3-verified): chunk p stores octet
// ko=(p&3)^((row>>1)&3); read slot=(quad^(row>>1))&3.
__global__ __launch_bounds__(256) void gemm_qkv_kernel(
    const bf16_t* __restrict__ A, const bf16_t* __restrict__ Bt,
    const float* __restrict__ bias, bf16_t* __restrict__ Cout,
    bf16_t* __restrict__ Vt, int Nn, int K) {
  constexpr int BM = 128, BN = 128, BK = 32;
  constexpr int TSZ = BM * BK;             // 4096 elems per A (or B) tile
  __shared__ __align__(16) bf16_t smem[3 * 2 * TSZ];   // 48 KB
  int tid = threadIdx.x;
  int wave = tid >> 6, lane = tid & 63;
  int c = lane & 15, quad = lane >> 4;
  int bm = blockIdx.x * BM;
  int bn = blockIdx.y * BN;
  int wm = (wave & 1) * 64, wn = (wave >> 1) * 64;
  f32x4 acc[4][4] = {};

  // staging descriptors: chunk p = i*256 + tid; row = p>>2 (4 chunks/row)
  const bf16_t* agp[2]; const bf16_t* bgp[2]; int ldo[2];
  #pragma unroll
  for (int i = 0; i < 2; ++i) {
    int p = i * 256 + tid;
    int row = p >> 2;
    int ko = (p & 3) ^ ((row >> 1) & 3);
    agp[i] = A + (size_t)(bm + row) * K + ko * 8;
    bgp[i] = Bt + (size_t)(bn + row) * K + ko * 8;
    ldo[i] = (i * 256 + wave * 64) * 8;   // elems within one tile buffer
  }

  auto stage = [&](int s) {
    bf16_t* ab = smem + (s % 3) * 2 * TSZ;
    bf16_t* bb = ab + TSZ;
    int ks = s * BK;
    #pragma unroll
    for (int i = 0; i < 2; ++i) {
      async_copy16(agp[i] + ks, ab + ldo[i]);
      async_copy16(bgp[i] + ks, bb + ldo[i]);
    }
  };

  auto compute = [&](int s) {
    const bf16_t* ab = smem + (s % 3) * 2 * TSZ;
    const bf16_t* bb = ab + TSZ;
    bf16x8 af[4], bf[4];
    #pragma unroll
    for (int mt = 0; mt < 4; ++mt) {
      int row = wm + mt * 16 + c;
      int slot = (quad ^ (row >> 1)) & 3;
      af[mt] = *(const bf16x8*)(ab + row * 32 + slot * 8);
    }
    #pragma unroll
    for (int nt = 0; nt < 4; ++nt) {
      int row = wn + nt * 16 + c;
      int slot = (quad ^ (row >> 1)) & 3;
      bf[nt] = *(const bf16x8*)(bb + row * 32 + slot * 8);
    }
    #pragma unroll
    for (int mt = 0; mt < 4; ++mt)
      #pragma unroll
      for (int nt = 0; nt < 4; ++nt)
        acc[mt][nt] = __builtin_amdgcn_mfma_f32_16x16x32_bf16(
            af[mt], bf[nt], acc[mt][nt], 0, 0, 0);
  };

  int nkb = K / BK;                 // 32
  stage(0); stage(1);
  for (int s = 0; s < nkb - 1; ++s) {
    asm volatile("s_waitcnt vmcnt(4)" ::: "memory");   // tile s landed
    __builtin_amdgcn_s_barrier();
    asm volatile("" ::: "memory");
    if (s + 2 < nkb) stage(s + 2);  // into buf[(s+2)%3] == buf[(s-1)%3], free
    compute(s);
  }
  asm volatile("s_waitcnt vmcnt(0)" ::: "memory");
  __builtin_amdgcn_s_barrier();
  asm volatile("" ::: "memory");
  compute(nkb - 1);

  // ---- epilogue: bias + Q-scale C-write, V^T emission (R1-verified) ----
  bool do_vt = (bn >= 2 * HID);
  bf16_t* tb = smem;               // 36 KB staging fits in 48 KB
  __syncthreads();                 // all ds_reads done before smem reuse

  #pragma unroll
  for (int nt = 0; nt < 4; ++nt) {
    int col = bn + wn + nt * 16 + c;
    float bv = bias[col];
    float sc = (col < HID) ? ATT_SCALE2 : 1.0f;
    #pragma unroll
    for (int mt = 0; mt < 4; ++mt) {
      #pragma unroll
      for (int r = 0; r < 4; ++r) {
        int loc = wm + mt * 16 + quad * 4 + r;
        float v = (acc[mt][nt][r] + bv) * sc;
        Cout[(size_t)(bm + loc) * Nn + col] = (bf16_t)v;
        if (do_vt) {
          int dg = wn + nt * 16 + c;
          int hh = dg >> 6, dl = dg & 63;
          tb[((loc & 1) * 2 + hh) * 4608 + dl * 72 + (loc >> 1)] = (bf16_t)v;
        }
      }
    }
  }

  if (do_vt) {
    __syncthreads();
    int h0 = (bn - 2 * HID) >> 6;
    int n2 = (tid & 7) * 8;
    #pragma unroll
    for (int i = 0; i < 2; ++i) {
      #pragma unroll
      for (int hh = 0; hh < 2; ++hh) {
        #pragma unroll
        for (int k = 0; k < 2; ++k) {
          int d = (tid >> 3) + k * 32;
          bf16x8 vv = *(const bf16x8*)(tb + ((i * 2 + hh) * 4608) + d * 72 + n2);
          *(bf16x8*)(Vt + (size_t)((i * 16 + h0 + hh) * HDIM + d) * N_SEQ + bm / 2 + n2) = vv;
        }
      }
    }
  }
}

// ---------------- 2-phase GEMM (out-projection, R1-verified) ---------------
template <int BM, int BN, bool OUT_BF16>
__global__ __launch_bounds__(256) void gemm_bt_kernel(
    const bf16_t* __restrict__ A, const bf16_t* __restrict__ Bt,
    const float* __restrict__ bias, void* __restrict__ Cout,
    int M, int Nn, int K) {
  constexpr int BK = 64;
  constexpr int MT = BM / 32;
  constexpr int NT = BN / 32;
  constexpr int CA = BM / 32;
  constexpr int CB = BN / 32;
  constexpr int ASZ = BM * BK;
  constexpr int BSZ = BN * BK;
  __shared__ __align__(16) bf16_t smem[2 * ASZ + 2 * BSZ];
  bf16_t* const Asb = smem;
  bf16_t* const Bsb = smem + 2 * ASZ;
  int tid = threadIdx.x;
  int wave = tid >> 6, lane = tid & 63;
  int c = lane & 15, quad = lane >> 4;
  int bm = blockIdx.x * BM;
  int bn = blockIdx.y * BN;
  int wm = (wave & 1) * (BM / 2), wn = (wave >> 1) * (BN / 2);
  f32x4 acc[MT][NT] = {};

  const bf16_t* agp[CA]; int alo[CA];
  const bf16_t* bgp[CB]; int blo[CB];
  #pragma unroll
  for (int i = 0; i < CA; ++i) {
    int p = i * 256 + tid;
    int row = p >> 3, ko = (p & 7) ^ (row & 7);
    agp[i] = A + (size_t)(bm + row) * K + ko * 8;
    alo[i] = (i * 256 + wave * 64) * 8;
  }
  #pragma unroll
  for (int i = 0; i < CB; ++i) {
    int p = i * 256 + tid;
    int row = p >> 3, ko = (p & 7) ^ (row & 7);
    bgp[i] = Bt + (size_t)(bn + row) * K + ko * 8;
    blo[i] = (i * 256 + wave * 64) * 8;
  }

  #pragma unroll
  for (int i = 0; i < CA; ++i) async_copy16(agp[i], Asb + alo[i]);
  #pragma unroll
  for (int i = 0; i < CB; ++i) async_copy16(bgp[i], Bsb + blo[i]);

  int nkb = K / BK;
  for (int ki = 0; ki < nkb; ++ki) {
    __syncthreads();
    if (ki + 1 < nkb) {
      int kb = (ki + 1) * BK;
      bf16_t* an = Asb + ((ki + 1) & 1) * ASZ;
      bf16_t* bnx = Bsb + ((ki + 1) & 1) * BSZ;
      #pragma unroll
      for (int i = 0; i < CA; ++i) async_copy16(agp[i] + kb, an + alo[i]);
      #pragma unroll
      for (int i = 0; i < CB; ++i) async_copy16(bgp[i] + kb, bnx + blo[i]);
    }
    const bf16_t* as = Asb + (ki & 1) * ASZ;
    const bf16_t* bs = Bsb + (ki & 1) * BSZ;
    #pragma unroll
    for (int kk = 0; kk < 2; ++kk) {
      bf16x8 af[MT], bf[NT];
      #pragma unroll
      for (int mt = 0; mt < MT; ++mt) {
        int row = wm + mt * 16 + c;
        int slot = (kk * 4 + quad) ^ (row & 7);
        af[mt] = *(const bf16x8*)(as + (size_t)(row * 8 + slot) * 8);
      }
      #pragma unroll
      for (int nt = 0; nt < NT; ++nt) {
        int row = wn + nt * 16 + c;
        int slot = (kk * 4 + quad) ^ (row & 7);
        bf[nt] = *(const bf16x8*)(bs + (size_t)(row * 8 + slot) * 8);
      }
      #pragma unroll
      for (int mt = 0; mt < MT; ++mt)
        #pragma unroll
        for (int nt = 0; nt < NT; ++nt)
          acc[mt][nt] = __builtin_amdgcn_mfma_f32_16x16x32_bf16(
              af[mt], bf[nt], acc[mt][nt], 0, 0, 0);
    }
  }

  #pragma unroll
  for (int nt = 0; nt < NT; ++nt) {
    int col = bn + wn + nt * 16 + c;
    float bv = bias[col];
    #pragma unroll
    for (int mt = 0; mt < MT; ++mt) {
      #pragma unroll
      for (int r = 0; r < 4; ++r) {
        int loc = wm + mt * 16 + quad * 4 + r;
        int row = bm + loc;
        float v = acc[mt][nt][r] + bv;
        if (OUT_BF16)
          ((bf16_t*)Cout)[(size_t)row * Nn + col] = (bf16_t)v;
        else
          ((float*)Cout)[(size_t)row * Nn + col] = v;
      }
    }
  }
}

// ---------------- flash attention (round-1 verified version) ---------------
__global__ __launch_bounds__(512, 4) void flash_attn_kernel(
    const bf16_t* __restrict__ Pj, const bf16_t* __restrict__ Vt,
    bf16_t* __restrict__ AO) {
  __shared__ __align__(16) bf16_t Ks[2][64 * 64];   // [j][d] swizzled
  __shared__ __align__(16) bf16_t Vs[2][64 * 64];   // [d][j] swizzled
  __shared__ __align__(16) bf16_t Ps[8][16 * 64];   // per-wave P[i][j] swizzled
  const int PJP = 3 * HID;
  int tid = threadIdx.x, wave = tid >> 6, lane = tid & 63;
  int c = lane & 15, quad = lane >> 4;
  int c7 = c & 7;
  int bid = blockIdx.x;
  int qb = (bid < 256) ? (15 - (bid >> 5)) : ((bid - 256) >> 5);
  int bh = bid & 31;
  int h = bh & 15, b = bh >> 4;
  int i0 = qb * 128;

  int i_row = i0 + wave * 16 + c;
  const bf16_t* qg = Pj + (size_t)(i_row * BATCH + b) * PJP + h * HDIM + quad * 8;
  bf16x8 qf0 = *(const bf16x8*)(qg);
  bf16x8 qf1 = *(const bf16x8*)(qg + 32);

  f32x4 o[4] = {};                   // O^T: rows d, col i=c
  float lrow = 0.f;

  int jr = tid >> 3, oc = tid & 7;
  int lds_off = jr * 64 + (oc ^ (jr & 7)) * 8;
  const bf16_t* kg0 = Pj + (size_t)b * PJP + HID + h * HDIM + oc * 8;
  const bf16_t* vg0 = Vt + (size_t)(bh * HDIM + jr) * N_SEQ + oc * 8;

  int njt = 2 * qb + 2;
  bf16x8 kreg = *(const bf16x8*)(kg0 + (size_t)jr * BATCH * PJP);
  bf16x8 vreg = *(const bf16x8*)(vg0);

  for (int jt = 0; jt < njt; ++jt) {
    bf16_t* ks = Ks[jt & 1];
    bf16_t* vs = Vs[jt & 1];
    *(bf16x8*)(ks + lds_off) = kreg;
    *(bf16x8*)(vs + lds_off) = vreg;
    __syncthreads();
    if (jt + 1 < njt) {
      int j0n = (jt + 1) * 64;
      kreg = *(const bf16x8*)(kg0 + (size_t)(j0n + jr) * BATCH * PJP);
      vreg = *(const bf16x8*)(vg0 + j0n);
    }

    f32x4 st[4];
    #pragma unroll
    for (int mt = 0; mt < 4; ++mt) {
      const bf16_t* kr = ks + (mt * 16 + c) * 64;
      bf16x8 ka0 = *(const bf16x8*)(kr + ((quad) ^ c7) * 8);
      bf16x8 ka1 = *(const bf16x8*)(kr + ((quad + 4) ^ c7) * 8);
      f32x4 s = {};
      s = __builtin_amdgcn_mfma_f32_16x16x32_bf16(ka0, qf0, s, 0, 0, 0);
      st[mt] = __builtin_amdgcn_mfma_f32_16x16x32_bf16(ka1, qf1, s, 0, 0, 0);
    }
    if (jt >= 2 * qb) {
      int j0 = jt * 64;
      int ig = i0 + wave * 16 + c;
      #pragma unroll
      for (int mt = 0; mt < 4; ++mt)
        #pragma unroll
        for (int r = 0; r < 4; ++r)
          if (j0 + mt * 16 + quad * 4 + r > ig) st[mt][r] = -1e30f;
    }

    #pragma unroll
    for (int mt = 0; mt < 4; ++mt)
      #pragma unroll
      for (int r = 0; r < 4; ++r) {
        st[mt][r] = EXP2F(st[mt][r]);
        lrow += st[mt][r];
      }

    bf16_t* pw = Ps[wave];
    #pragma unroll
    for (int mt = 0; mt < 4; ++mt) {
      bf16x4 pv;
      #pragma unroll
      for (int r = 0; r < 4; ++r) pv[r] = (bf16_t)st[mt][r];
      int joct = mt * 2 + (quad >> 1);
      *(bf16x4*)(pw + c * 64 + (joct ^ c7) * 8 + (quad & 1) * 4) = pv;
    }
    const bf16_t* pr = pw + c * 64;
    bf16x8 pa0 = *(const bf16x8*)(pr + ((quad) ^ c7) * 8);
    bf16x8 pa1 = *(const bf16x8*)(pr + ((quad + 4) ^ c7) * 8);

    #pragma unroll
    for (int nt = 0; nt < 4; ++nt) {
      const bf16_t* vr = vs + (nt * 16 + c) * 64;
      bf16x8 vb0 = *(const bf16x8*)(vr + ((quad) ^ c7) * 8);
      bf16x8 vb1 = *(const bf16x8*)(vr + ((quad + 4) ^ c7) * 8);
      o[nt] = __builtin_amdgcn_mfma_f32_16x16x32_bf16(vb0, pa0, o[nt], 0, 0, 0);
      o[nt] = __builtin_amdgcn_mfma_f32_16x16x32_bf16(vb1, pa1, o[nt], 0, 0, 0);
    }
  }

  float lfull = lrow;
  lfull += __shfl_xor(lfull, 16);
  lfull += __shfl_xor(lfull, 32);
  float linv = 1.0f / lfull;
  int orow = (i0 + wave * 16 + c) * BATCH + b;
  #pragma unroll
  for (int nt = 0; nt < 4; ++nt) {
    bf16x4 pv;
    #pragma unroll
    for (int r = 0; r < 4; ++r) pv[r] = (bf16_t)(o[nt][r] * linv);
    *(bf16x4*)(AO + (size_t)orow * HID + h * HDIM + nt * 16 + quad * 4) = pv;
  }
}

extern "C" void kernel_launch(void* const* d_in, const int* in_sizes, int n_in,
                              void* d_out, int out_size, void* d_ws, size_t ws_size,
                              hipStream_t stream) {
  const float* x      = (const float*)d_in[0];   // [2048][2][1024]
  const float* W_proj = (const float*)d_in[1];   // [1024][3072]
  const float* b_proj = (const float*)d_in[2];   // [3072]
  const float* W_out  = (const float*)d_in[3];   // [1024][1024]
  const float* b_out  = (const float*)d_in[4];   // [1024]

  bf16_t* Xb  = (bf16_t*)d_ws;                               // 4096*1024
  bf16_t* Wpt = Xb  + (size_t)NBROW * EMB;                   // 3072*1024
  bf16_t* Wot = Wpt + (size_t)3 * HID * EMB;                 // 1024*1024
  bf16_t* Pj  = Wot + (size_t)HID * EMB;                     // 4096*3072
  bf16_t* AO  = Pj  + (size_t)NBROW * 3 * HID;               // 4096*1024
  bf16_t* Vt  = AO  + (size_t)NBROW * HID;                   // 32*64*2048

  prep_kernel<<<8192, 256, 0, stream>>>(x, W_proj, W_out, Xb, Wpt, Wot);
  gemm_qkv_kernel<<<dim3(NBROW / 128, 3 * HID / 128), 256, 0, stream>>>(
      Xb, Wpt, b_proj, Pj, Vt, 3 * HID, EMB);
  flash_attn_kernel<<<512, 512, 0, stream>>>(Pj, Vt, AO);
  gemm_bt_kernel<128, 128, false>
      <<<dim3(NBROW / 128, EMB / 128), 256, 0, stream>>>(
      AO, Wot, b_out, d_out, NBROW, EMB, HID);
}

// Round 9
// 159.590 us; speedup vs baseline: 1.0783x; 1.0145x over previous
//
#include <hip/hip_runtime.h>
#include <cstdint>
#include <cstddef>

typedef __bf16 bf16_t;
typedef __bf16 bf16x8 __attribute__((ext_vector_type(8)));
typedef __bf16 bf16x4 __attribute__((ext_vector_type(4)));
typedef float f32x4 __attribute__((ext_vector_type(4)));

#define N_SEQ 2048
#define BATCH 2
#define EMB   1024
#define HID   1024
#define NHEAD 16
#define HDIM  64
#define NBROW (N_SEQ * BATCH)   /* 4096 GEMM rows (n*B+b) */
#define ATT_SCALE2 (0.03125f * 1.44269504f)  /* 1/sqrt(1024) * log2(e) */

#define EXP2F(x) __builtin_amdgcn_exp2f(x)   /* __exp2f collides with glibc macro */

static __device__ __forceinline__ void async_copy16(const bf16_t* g, bf16_t* l) {
  __builtin_amdgcn_global_load_lds((const __attribute__((address_space(1))) void*)g,
                                   (__attribute__((address_space(3))) void*)l,
                                   16, 0, 0);
}

// ---------------- fused prep: convert x + transpose both weights -----------
__global__ __launch_bounds__(256) void prep_kernel(
    const float* __restrict__ x, const float* __restrict__ Wp,
    const float* __restrict__ Wo, bf16_t* __restrict__ Xb,
    bf16_t* __restrict__ Wpt, bf16_t* __restrict__ Wot) {
  int bid = blockIdx.x;
  if (bid < 4096) {
    int i = (bid * 256 + threadIdx.x) * 4;
    float4 v = *(const float4*)(x + i);
    bf16x4 o;
    o[0] = (bf16_t)v.x; o[1] = (bf16_t)v.y; o[2] = (bf16_t)v.z; o[3] = (bf16_t)v.w;
    *(bf16x4*)(Xb + i) = o;
    return;
  }
  __shared__ float tile[32][33];
  const float* in; bf16_t* out; int R, C, bx;
  if (bid < 4096 + 3072) { bx = bid - 4096; in = Wp; out = Wpt; R = 1024; C = 3072; }
  else                   { bx = bid - 7168; in = Wo; out = Wot; R = 1024; C = 1024; }
  int gx = C / 32;
  int bc = (bx % gx) * 32, br = (bx / gx) * 32;
  int tx = threadIdx.x & 31, ty = threadIdx.x >> 5;   // 32 x 8
  #pragma unroll
  for (int i = 0; i < 32; i += 8)
    tile[ty + i][tx] = in[(size_t)(br + ty + i) * C + bc + tx];
  __syncthreads();
  #pragma unroll
  for (int i = 0; i < 32; i += 8)
    out[(size_t)(bc + ty + i) * R + br + tx] = (bf16_t)tile[tx][ty + i];
}

// ---------------- pipelined GEMM: C = A * Bt^T + bias ----------------------
// Round-1 verified version (BM=128, BN=128): one barrier per K-iter,
// double-buffered global_load_lds, 0-conflict XOR swizzle.
template <int BM, int BN, bool OUT_BF16, bool SCALEQ, bool WRITE_VT>
__global__ __launch_bounds__(256) void gemm_bt_kernel(
    const bf16_t* __restrict__ A, const bf16_t* __restrict__ Bt,
    const float* __restrict__ bias, void* __restrict__ Cout,
    bf16_t* __restrict__ Vt, int M, int Nn, int K) {
  constexpr int BK = 64;
  constexpr int MT = BM / 32;
  constexpr int NT = BN / 32;
  constexpr int CA = BM / 32;              // A 16B-chunks per thread
  constexpr int CB = BN / 32;              // B 16B-chunks per thread
  constexpr int ASZ = BM * BK;             // elems per A buffer
  constexpr int BSZ = BN * BK;             // elems per B buffer
  __shared__ __align__(16) bf16_t smem[2 * ASZ + 2 * BSZ];
  bf16_t* const Asb = smem;
  bf16_t* const Bsb = smem + 2 * ASZ;
  int tid = threadIdx.x;
  int wave = tid >> 6, lane = tid & 63;
  int c = lane & 15, quad = lane >> 4;
  int bm = blockIdx.x * BM;
  int bn = blockIdx.y * BN;
  int wm = (wave & 1) * (BM / 2), wn = (wave >> 1) * (BN / 2);
  f32x4 acc[MT][NT] = {};

  const bf16_t* agp[CA]; int alo[CA];
  const bf16_t* bgp[CB]; int blo[CB];
  #pragma unroll
  for (int i = 0; i < CA; ++i) {
    int p = i * 256 + tid;
    int row = p >> 3, ko = (p & 7) ^ (row & 7);
    agp[i] = A + (size_t)(bm + row) * K + ko * 8;
    alo[i] = (i * 256 + wave * 64) * 8;
  }
  #pragma unroll
  for (int i = 0; i < CB; ++i) {
    int p = i * 256 + tid;
    int row = p >> 3, ko = (p & 7) ^ (row & 7);
    bgp[i] = Bt + (size_t)(bn + row) * K + ko * 8;
    blo[i] = (i * 256 + wave * 64) * 8;
  }

  #pragma unroll
  for (int i = 0; i < CA; ++i) async_copy16(agp[i], Asb + alo[i]);
  #pragma unroll
  for (int i = 0; i < CB; ++i) async_copy16(bgp[i], Bsb + blo[i]);

  int nkb = K / BK;
  for (int ki = 0; ki < nkb; ++ki) {
    __syncthreads();   // drains tile-ki loads (issued one compute phase ago)
    if (ki + 1 < nkb) {
      int kb = (ki + 1) * BK;
      bf16_t* an = Asb + ((ki + 1) & 1) * ASZ;
      bf16_t* bnx = Bsb + ((ki + 1) & 1) * BSZ;
      #pragma unroll
      for (int i = 0; i < CA; ++i) async_copy16(agp[i] + kb, an + alo[i]);
      #pragma unroll
      for (int i = 0; i < CB; ++i) async_copy16(bgp[i] + kb, bnx + blo[i]);
    }
    const bf16_t* as = Asb + (ki & 1) * ASZ;
    const bf16_t* bs = Bsb + (ki & 1) * BSZ;
    #pragma unroll
    for (int kk = 0; kk < 2; ++kk) {
      bf16x8 af[MT], bf[NT];
      #pragma unroll
      for (int mt = 0; mt < MT; ++mt) {
        int row = wm + mt * 16 + c;
        int slot = (kk * 4 + quad) ^ (row & 7);
        af[mt] = *(const bf16x8*)(as + (size_t)(row * 8 + slot) * 8);
      }
      #pragma unroll
      for (int nt = 0; nt < NT; ++nt) {
        int row = wn + nt * 16 + c;
        int slot = (kk * 4 + quad) ^ (row & 7);
        bf[nt] = *(const bf16x8*)(bs + (size_t)(row * 8 + slot) * 8);
      }
      #pragma unroll
      for (int mt = 0; mt < MT; ++mt)
        #pragma unroll
        for (int nt = 0; nt < NT; ++nt)
          acc[mt][nt] = __builtin_amdgcn_mfma_f32_16x16x32_bf16(
              af[mt], bf[nt], acc[mt][nt], 0, 0, 0);
    }
  }

  bool do_vt = WRITE_VT && (bn >= 2 * HID);
  bf16_t* tb = smem;             // reuse staging LDS for V^T: 4*64*72*2B = 36KB
  if (do_vt) __syncthreads();    // last tile's ds_reads done before smem reuse

  #pragma unroll
  for (int nt = 0; nt < NT; ++nt) {
    int col = bn + wn + nt * 16 + c;
    float bv = bias[col];
    float sc = (SCALEQ && col < HID) ? ATT_SCALE2 : 1.0f;
    #pragma unroll
    for (int mt = 0; mt < MT; ++mt) {
      #pragma unroll
      for (int r = 0; r < 4; ++r) {
        int loc = wm + mt * 16 + quad * 4 + r;        // row within tile
        int row = bm + loc;                           // C layout: row=(lane>>4)*4+reg
        float v = (acc[mt][nt][r] + bv) * sc;
        if (OUT_BF16)
          ((bf16_t*)Cout)[(size_t)row * Nn + col] = (bf16_t)v;
        else
          ((float*)Cout)[(size_t)row * Nn + col] = v;
        if (do_vt) {
          int dg = wn + nt * 16 + c;                  // col within tile [0,128)
          int hh = dg >> 6, dl = dg & 63;             // head-half, d within head
          tb[((loc & 1) * 2 + hh) * 4608 + dl * 72 + (loc >> 1)] = (bf16_t)v;
        }
      }
    }
  }

  if (do_vt) {
    __syncthreads();
    int h0 = (bn - 2 * HID) >> 6;        // first of the 2 heads in this tile
    int n2 = (tid & 7) * 8;
    #pragma unroll
    for (int i = 0; i < 2; ++i) {        // batch b
      #pragma unroll
      for (int hh = 0; hh < 2; ++hh) {   // head within tile
        #pragma unroll
        for (int k = 0; k < 2; ++k) {
          int d = (tid >> 3) + k * 32;
          bf16x8 vv = *(const bf16x8*)(tb + ((i * 2 + hh) * 4608) + d * 72 + n2);
          *(bf16x8*)(Vt + (size_t)((i * 16 + h0 + hh) * HDIM + d) * N_SEQ + bm / 2 + n2) = vv;
        }
      }
    }
  }
}

// ---------------- flash attention: T15 two-tile pipeline -------------------
// R1 structure + software pipeline: at iter jt the wave holds raw S(jt);
// it issues QK(jt+1) MFMAs FIRST, then mask/exp/pack of S(jt) (independent
// -> VALU interleaves under the MFMAs), then PV(jt). Triple-buffered K/V
// keeps ONE barrier per iter:
//   RAW: QK(jt+1) reads buf[(jt+1)%3], written iter jt-1, published by this
//        iter's top barrier (prologue barrier for jt=0).
//   WAR: this iter writes buf[(jt+2)%3]; its last readers (QK(jt) / PV(jt-1))
//        ran before this iter's top barrier.
// LDS: 3*(8+8) + 16 = 64 KB -> 2 blocks/CU.
__global__ __launch_bounds__(512, 4) void flash_attn_kernel(
    const bf16_t* __restrict__ Pj, const bf16_t* __restrict__ Vt,
    bf16_t* __restrict__ AO) {
  __shared__ __align__(16) bf16_t Ks[3][64 * 64];   // [j][d] swizzled
  __shared__ __align__(16) bf16_t Vs[3][64 * 64];   // [d][j] swizzled
  __shared__ __align__(16) bf16_t Ps[8][16 * 64];   // per-wave P[i][j] swizzled
  const int PJP = 3 * HID;
  int tid = threadIdx.x, wave = tid >> 6, lane = tid & 63;
  int c = lane & 15, quad = lane >> 4;
  int c7 = c & 7;
  int bid = blockIdx.x;
  int qb = (bid < 256) ? (15 - (bid >> 5)) : ((bid - 256) >> 5);
  int bh = bid & 31;
  int h = bh & 15, b = bh >> 4;
  int i0 = qb * 128;

  int i_row = i0 + wave * 16 + c;
  const bf16_t* qg = Pj + (size_t)(i_row * BATCH + b) * PJP + h * HDIM + quad * 8;
  bf16x8 qf0 = *(const bf16x8*)(qg);
  bf16x8 qf1 = *(const bf16x8*)(qg + 32);

  f32x4 o[4] = {};                   // O^T: rows d, col i=c
  float lrow = 0.f;

  int jr = tid >> 3, oc = tid & 7;
  int lds_off = jr * 64 + (oc ^ (jr & 7)) * 8;
  const bf16_t* kg0 = Pj + (size_t)b * PJP + HID + h * HDIM + oc * 8;
  const bf16_t* vg0 = Vt + (size_t)(bh * HDIM + jr) * N_SEQ + oc * 8;

  int njt = 2 * qb + 2;              // always >= 2

  // ---- prologue: stage tiles 0,1; QK(0); prefetch tile 2 ----
  bf16x8 kreg = *(const bf16x8*)(kg0 + (size_t)jr * BATCH * PJP);
  bf16x8 vreg = *(const bf16x8*)(vg0);
  *(bf16x8*)(Ks[0] + lds_off) = kreg;
  *(bf16x8*)(Vs[0] + lds_off) = vreg;
  kreg = *(const bf16x8*)(kg0 + (size_t)(64 + jr) * BATCH * PJP);
  vreg = *(const bf16x8*)(vg0 + 64);
  *(bf16x8*)(Ks[1] + lds_off) = kreg;
  *(bf16x8*)(Vs[1] + lds_off) = vreg;
  __syncthreads();                   // publish buffers 0 and 1

  f32x4 st[4];
  #pragma unroll
  for (int mt = 0; mt < 4; ++mt) {
    const bf16_t* kr = Ks[0] + (mt * 16 + c) * 64;
    bf16x8 ka0 = *(const bf16x8*)(kr + ((quad) ^ c7) * 8);
    bf16x8 ka1 = *(const bf16x8*)(kr + ((quad + 4) ^ c7) * 8);
    f32x4 s = {};
    s = __builtin_amdgcn_mfma_f32_16x16x32_bf16(ka0, qf0, s, 0, 0, 0);
    st[mt] = __builtin_amdgcn_mfma_f32_16x16x32_bf16(ka1, qf1, s, 0, 0, 0);
  }
  if (njt > 2) {
    kreg = *(const bf16x8*)(kg0 + (size_t)(128 + jr) * BATCH * PJP);
    vreg = *(const bf16x8*)(vg0 + 128);
  }

  for (int jt = 0; jt < njt; ++jt) {
    if (jt) __syncthreads();         // publish buf[(jt+1)%3]; WAR-guard buf[(jt+2)%3]
    if (jt + 2 < njt) {              // write tile jt+2 (regs loaded one iter ago)
      *(bf16x8*)(Ks[(jt + 2) % 3] + lds_off) = kreg;
      *(bf16x8*)(Vs[(jt + 2) % 3] + lds_off) = vreg;
    }
    if (jt + 3 < njt) {              // prefetch tile jt+3 into regs
      int j0n = (jt + 3) * 64;
      kreg = *(const bf16x8*)(kg0 + (size_t)(j0n + jr) * BATCH * PJP);
      vreg = *(const bf16x8*)(vg0 + j0n);
    }

    // QK(jt+1) issued BEFORE the exp of tile jt (independent -> interleave)
    f32x4 stN[4];
    bool more = (jt + 1 < njt);
    if (more) {
      const bf16_t* ks = Ks[(jt + 1) % 3];
      #pragma unroll
      for (int mt = 0; mt < 4; ++mt) {
        const bf16_t* kr = ks + (mt * 16 + c) * 64;
        bf16x8 ka0 = *(const bf16x8*)(kr + ((quad) ^ c7) * 8);
        bf16x8 ka1 = *(const bf16x8*)(kr + ((quad + 4) ^ c7) * 8);
        f32x4 s = {};
        s = __builtin_amdgcn_mfma_f32_16x16x32_bf16(ka0, qf0, s, 0, 0, 0);
        stN[mt] = __builtin_amdgcn_mfma_f32_16x16x32_bf16(ka1, qf1, s, 0, 0, 0);
      }
    }

    // ---- softmax finish of tile jt (VALU, overlaps QK above) ----
    if (jt >= 2 * qb) {
      int j0 = jt * 64;
      int ig = i0 + wave * 16 + c;
      #pragma unroll
      for (int mt = 0; mt < 4; ++mt)
        #pragma unroll
        for (int r = 0; r < 4; ++r)
          if (j0 + mt * 16 + quad * 4 + r > ig) st[mt][r] = -1e30f;
    }
    #pragma unroll
    for (int mt = 0; mt < 4; ++mt)
      #pragma unroll
      for (int r = 0; r < 4; ++r) {
        st[mt][r] = EXP2F(st[mt][r]);
        lrow += st[mt][r];
      }

    bf16_t* pw = Ps[wave];
    #pragma unroll
    for (int mt = 0; mt < 4; ++mt) {
      bf16x4 pv;
      #pragma unroll
      for (int r = 0; r < 4; ++r) pv[r] = (bf16_t)st[mt][r];
      int joct = mt * 2 + (quad >> 1);
      *(bf16x4*)(pw + c * 64 + (joct ^ c7) * 8 + (quad & 1) * 4) = pv;
    }
    const bf16_t* pr = pw + c * 64;
    bf16x8 pa0 = *(const bf16x8*)(pr + ((quad) ^ c7) * 8);
    bf16x8 pa1 = *(const bf16x8*)(pr + ((quad + 4) ^ c7) * 8);

    const bf16_t* vs = Vs[jt % 3];
    #pragma unroll
    for (int nt = 0; nt < 4; ++nt) {
      const bf16_t* vr = vs + (nt * 16 + c) * 64;
      bf16x8 vb0 = *(const bf16x8*)(vr + ((quad) ^ c7) * 8);
      bf16x8 vb1 = *(const bf16x8*)(vr + ((quad + 4) ^ c7) * 8);
      o[nt] = __builtin_amdgcn_mfma_f32_16x16x32_bf16(vb0, pa0, o[nt], 0, 0, 0);
      o[nt] = __builtin_amdgcn_mfma_f32_16x16x32_bf16(vb1, pa1, o[nt], 0, 0, 0);
    }

    if (more) {
      #pragma unroll
      for (int mt = 0; mt < 4; ++mt) st[mt] = stN[mt];
    }
  }

  float lfull = lrow;
  lfull += __shfl_xor(lfull, 16);
  lfull += __shfl_xor(lfull, 32);
  float linv = 1.0f / lfull;
  int orow = (i0 + wave * 16 + c) * BATCH + b;
  #pragma unroll
  for (int nt = 0; nt < 4; ++nt) {
    bf16x4 pv;
    #pragma unroll
    for (int r = 0; r < 4; ++r) pv[r] = (bf16_t)(o[nt][r] * linv);
    *(bf16x4*)(AO + (size_t)orow * HID + h * HDIM + nt * 16 + quad * 4) = pv;
  }
}

extern "C" void kernel_launch(void* const* d_in, const int* in_sizes, int n_in,
                              void* d_out, int out_size, void* d_ws, size_t ws_size,
                              hipStream_t stream) {
  const float* x      = (const float*)d_in[0];   // [2048][2][1024]
  const float* W_proj = (const float*)d_in[1];   // [1024][3072]
  const float* b_proj = (const float*)d_in[2];   // [3072]
  const float* W_out  = (const float*)d_in[3];   // [1024][1024]
  const float* b_out  = (const float*)d_in[4];   // [1024]

  bf16_t* Xb  = (bf16_t*)d_ws;                               // 4096*1024
  bf16_t* Wpt = Xb  + (size_t)NBROW * EMB;                   // 3072*1024
  bf16_t* Wot = Wpt + (size_t)3 * HID * EMB;                 // 1024*1024
  bf16_t* Pj  = Wot + (size_t)HID * EMB;                     // 4096*3072
  bf16_t* AO  = Pj  + (size_t)NBROW * 3 * HID;               // 4096*1024
  bf16_t* Vt  = AO  + (size_t)NBROW * HID;                   // 32*64*2048

  prep_kernel<<<8192, 256, 0, stream>>>(x, W_proj, W_out, Xb, Wpt, Wot);
  gemm_bt_kernel<128, 128, true, true, true>
      <<<dim3(NBROW / 128, 3 * HID / 128), 256, 0, stream>>>(
      Xb, Wpt, b_proj, (void*)Pj, Vt, NBROW, 3 * HID, EMB);
  flash_attn_kernel<<<512, 512, 0, stream>>>(Pj, Vt, AO);
  gemm_bt_kernel<128, 128, false, false, false>
      <<<dim3(NBROW / 128, EMB / 128), 256, 0, stream>>>(
      AO, Wot, b_out, d_out, nullptr, NBROW, EMB, HID);
}

// Round 10
// 157.676 us; speedup vs baseline: 1.0914x; 1.0121x over previous
//
#include <hip/hip_runtime.h>
#include <cstdint>
#include <cstddef>

typedef __bf16 bf16_t;
typedef __bf16 bf16x8 __attribute__((ext_vector_type(8)));
typedef __bf16 bf16x4 __attribute__((ext_vector_type(4)));
typedef float f32x4 __attribute__((ext_vector_type(4)));

#define N_SEQ 2048
#define BATCH 2
#define EMB   1024
#define HID   1024
#define NHEAD 16
#define HDIM  64
#define NBROW (N_SEQ * BATCH)   /* 4096 GEMM rows (n*B+b) */
#define ATT_SCALE2 (0.03125f * 1.44269504f)  /* 1/sqrt(1024) * log2(e) */

#define EXP2F(x) __builtin_amdgcn_exp2f(x)   /* __exp2f collides with glibc macro */

static __device__ __forceinline__ void async_copy16(const bf16_t* g, bf16_t* l) {
  __builtin_amdgcn_global_load_lds((const __attribute__((address_space(1))) void*)g,
                                   (__attribute__((address_space(3))) void*)l,
                                   16, 0, 0);
}

// ---------------- fused prep: convert x + transpose both weights -----------
__global__ __launch_bounds__(256) void prep_kernel(
    const float* __restrict__ x, const float* __restrict__ Wp,
    const float* __restrict__ Wo, bf16_t* __restrict__ Xb,
    bf16_t* __restrict__ Wpt, bf16_t* __restrict__ Wot) {
  int bid = blockIdx.x;
  if (bid < 4096) {
    int i = (bid * 256 + threadIdx.x) * 4;
    float4 v = *(const float4*)(x + i);
    bf16x4 o;
    o[0] = (bf16_t)v.x; o[1] = (bf16_t)v.y; o[2] = (bf16_t)v.z; o[3] = (bf16_t)v.w;
    *(bf16x4*)(Xb + i) = o;
    return;
  }
  __shared__ float tile[32][33];
  const float* in; bf16_t* out; int R, C, bx;
  if (bid < 4096 + 3072) { bx = bid - 4096; in = Wp; out = Wpt; R = 1024; C = 3072; }
  else                   { bx = bid - 7168; in = Wo; out = Wot; R = 1024; C = 1024; }
  int gx = C / 32;
  int bc = (bx % gx) * 32, br = (bx / gx) * 32;
  int tx = threadIdx.x & 31, ty = threadIdx.x >> 5;   // 32 x 8
  #pragma unroll
  for (int i = 0; i < 32; i += 8)
    tile[ty + i][tx] = in[(size_t)(br + ty + i) * C + bc + tx];
  __syncthreads();
  #pragma unroll
  for (int i = 0; i < 32; i += 8)
    out[(size_t)(bc + ty + i) * R + br + tx] = (bf16_t)tile[tx][ty + i];
}

// ---------------- pipelined GEMM: C = A * Bt^T + bias ----------------------
// Round-1 verified version: one barrier per K-iter, double-buffered
// global_load_lds, 0-conflict XOR swizzle. <128,64> instantiation (out-GEMM)
// verified in R0.
template <int BM, int BN, bool OUT_BF16, bool SCALEQ, bool WRITE_VT>
__global__ __launch_bounds__(256) void gemm_bt_kernel(
    const bf16_t* __restrict__ A, const bf16_t* __restrict__ Bt,
    const float* __restrict__ bias, void* __restrict__ Cout,
    bf16_t* __restrict__ Vt, int M, int Nn, int K) {
  constexpr int BK = 64;
  constexpr int MT = BM / 32;
  constexpr int NT = BN / 32;
  constexpr int CA = BM / 32;              // A 16B-chunks per thread
  constexpr int CB = BN / 32;              // B 16B-chunks per thread
  constexpr int ASZ = BM * BK;             // elems per A buffer
  constexpr int BSZ = BN * BK;             // elems per B buffer
  __shared__ __align__(16) bf16_t smem[2 * ASZ + 2 * BSZ];
  bf16_t* const Asb = smem;
  bf16_t* const Bsb = smem + 2 * ASZ;
  int tid = threadIdx.x;
  int wave = tid >> 6, lane = tid & 63;
  int c = lane & 15, quad = lane >> 4;
  int bm = blockIdx.x * BM;
  int bn = blockIdx.y * BN;
  int wm = (wave & 1) * (BM / 2), wn = (wave >> 1) * (BN / 2);
  f32x4 acc[MT][NT] = {};

  const bf16_t* agp[CA]; int alo[CA];
  const bf16_t* bgp[CB]; int blo[CB];
  #pragma unroll
  for (int i = 0; i < CA; ++i) {
    int p = i * 256 + tid;
    int row = p >> 3, ko = (p & 7) ^ (row & 7);
    agp[i] = A + (size_t)(bm + row) * K + ko * 8;
    alo[i] = (i * 256 + wave * 64) * 8;
  }
  #pragma unroll
  for (int i = 0; i < CB; ++i) {
    int p = i * 256 + tid;
    int row = p >> 3, ko = (p & 7) ^ (row & 7);
    bgp[i] = Bt + (size_t)(bn + row) * K + ko * 8;
    blo[i] = (i * 256 + wave * 64) * 8;
  }

  #pragma unroll
  for (int i = 0; i < CA; ++i) async_copy16(agp[i], Asb + alo[i]);
  #pragma unroll
  for (int i = 0; i < CB; ++i) async_copy16(bgp[i], Bsb + blo[i]);

  int nkb = K / BK;
  for (int ki = 0; ki < nkb; ++ki) {
    __syncthreads();   // drains tile-ki loads (issued one compute phase ago)
    if (ki + 1 < nkb) {
      int kb = (ki + 1) * BK;
      bf16_t* an = Asb + ((ki + 1) & 1) * ASZ;
      bf16_t* bnx = Bsb + ((ki + 1) & 1) * BSZ;
      #pragma unroll
      for (int i = 0; i < CA; ++i) async_copy16(agp[i] + kb, an + alo[i]);
      #pragma unroll
      for (int i = 0; i < CB; ++i) async_copy16(bgp[i] + kb, bnx + blo[i]);
    }
    const bf16_t* as = Asb + (ki & 1) * ASZ;
    const bf16_t* bs = Bsb + (ki & 1) * BSZ;
    #pragma unroll
    for (int kk = 0; kk < 2; ++kk) {
      bf16x8 af[MT], bf[NT];
      #pragma unroll
      for (int mt = 0; mt < MT; ++mt) {
        int row = wm + mt * 16 + c;
        int slot = (kk * 4 + quad) ^ (row & 7);
        af[mt] = *(const bf16x8*)(as + (size_t)(row * 8 + slot) * 8);
      }
      #pragma unroll
      for (int nt = 0; nt < NT; ++nt) {
        int row = wn + nt * 16 + c;
        int slot = (kk * 4 + quad) ^ (row & 7);
        bf[nt] = *(const bf16x8*)(bs + (size_t)(row * 8 + slot) * 8);
      }
      #pragma unroll
      for (int mt = 0; mt < MT; ++mt)
        #pragma unroll
        for (int nt = 0; nt < NT; ++nt)
          acc[mt][nt] = __builtin_amdgcn_mfma_f32_16x16x32_bf16(
              af[mt], bf[nt], acc[mt][nt], 0, 0, 0);
    }
  }

  bool do_vt = WRITE_VT && (bn >= 2 * HID);
  bf16_t* tb = smem;             // reuse staging LDS for V^T: 4*64*72*2B = 36KB
  if (do_vt) __syncthreads();    // last tile's ds_reads done before smem reuse

  #pragma unroll
  for (int nt = 0; nt < NT; ++nt) {
    int col = bn + wn + nt * 16 + c;
    float bv = bias[col];
    float sc = (SCALEQ && col < HID) ? ATT_SCALE2 : 1.0f;
    #pragma unroll
    for (int mt = 0; mt < MT; ++mt) {
      #pragma unroll
      for (int r = 0; r < 4; ++r) {
        int loc = wm + mt * 16 + quad * 4 + r;        // row within tile
        int row = bm + loc;                           // C layout: row=(lane>>4)*4+reg
        float v = (acc[mt][nt][r] + bv) * sc;
        if (OUT_BF16)
          ((bf16_t*)Cout)[(size_t)row * Nn + col] = (bf16_t)v;
        else
          ((float*)Cout)[(size_t)row * Nn + col] = v;
        if (do_vt) {
          int dg = wn + nt * 16 + c;                  // col within tile [0,128)
          int hh = dg >> 6, dl = dg & 63;             // head-half, d within head
          tb[((loc & 1) * 2 + hh) * 4608 + dl * 72 + (loc >> 1)] = (bf16_t)v;
        }
      }
    }
  }

  if (do_vt) {
    __syncthreads();
    int h0 = (bn - 2 * HID) >> 6;        // first of the 2 heads in this tile
    int n2 = (tid & 7) * 8;
    #pragma unroll
    for (int i = 0; i < 2; ++i) {        // batch b
      #pragma unroll
      for (int hh = 0; hh < 2; ++hh) {   // head within tile
        #pragma unroll
        for (int k = 0; k < 2; ++k) {
          int d = (tid >> 3) + k * 32;
          bf16x8 vv = *(const bf16x8*)(tb + ((i * 2 + hh) * 4608) + d * 72 + n2);
          *(bf16x8*)(Vt + (size_t)((i * 16 + h0 + hh) * HDIM + d) * N_SEQ + bm / 2 + n2) = vv;
        }
      }
    }
  }
}

// ---------------- flash attention: T15 two-tile pipeline (R9-verified) -----
__global__ __launch_bounds__(512, 4) void flash_attn_kernel(
    const bf16_t* __restrict__ Pj, const bf16_t* __restrict__ Vt,
    bf16_t* __restrict__ AO) {
  __shared__ __align__(16) bf16_t Ks[3][64 * 64];   // [j][d] swizzled
  __shared__ __align__(16) bf16_t Vs[3][64 * 64];   // [d][j] swizzled
  __shared__ __align__(16) bf16_t Ps[8][16 * 64];   // per-wave P[i][j] swizzled
  const int PJP = 3 * HID;
  int tid = threadIdx.x, wave = tid >> 6, lane = tid & 63;
  int c = lane & 15, quad = lane >> 4;
  int c7 = c & 7;
  int bid = blockIdx.x;
  int qb = (bid < 256) ? (15 - (bid >> 5)) : ((bid - 256) >> 5);
  int bh = bid & 31;
  int h = bh & 15, b = bh >> 4;
  int i0 = qb * 128;

  int i_row = i0 + wave * 16 + c;
  const bf16_t* qg = Pj + (size_t)(i_row * BATCH + b) * PJP + h * HDIM + quad * 8;
  bf16x8 qf0 = *(const bf16x8*)(qg);
  bf16x8 qf1 = *(const bf16x8*)(qg + 32);

  f32x4 o[4] = {};                   // O^T: rows d, col i=c
  float lrow = 0.f;

  int jr = tid >> 3, oc = tid & 7;
  int lds_off = jr * 64 + (oc ^ (jr & 7)) * 8;
  const bf16_t* kg0 = Pj + (size_t)b * PJP + HID + h * HDIM + oc * 8;
  const bf16_t* vg0 = Vt + (size_t)(bh * HDIM + jr) * N_SEQ + oc * 8;

  int njt = 2 * qb + 2;              // always >= 2

  // ---- prologue: stage tiles 0,1; QK(0); prefetch tile 2 ----
  bf16x8 kreg = *(const bf16x8*)(kg0 + (size_t)jr * BATCH * PJP);
  bf16x8 vreg = *(const bf16x8*)(vg0);
  *(bf16x8*)(Ks[0] + lds_off) = kreg;
  *(bf16x8*)(Vs[0] + lds_off) = vreg;
  kreg = *(const bf16x8*)(kg0 + (size_t)(64 + jr) * BATCH * PJP);
  vreg = *(const bf16x8*)(vg0 + 64);
  *(bf16x8*)(Ks[1] + lds_off) = kreg;
  *(bf16x8*)(Vs[1] + lds_off) = vreg;
  __syncthreads();                   // publish buffers 0 and 1

  f32x4 st[4];
  #pragma unroll
  for (int mt = 0; mt < 4; ++mt) {
    const bf16_t* kr = Ks[0] + (mt * 16 + c) * 64;
    bf16x8 ka0 = *(const bf16x8*)(kr + ((quad) ^ c7) * 8);
    bf16x8 ka1 = *(const bf16x8*)(kr + ((quad + 4) ^ c7) * 8);
    f32x4 s = {};
    s = __builtin_amdgcn_mfma_f32_16x16x32_bf16(ka0, qf0, s, 0, 0, 0);
    st[mt] = __builtin_amdgcn_mfma_f32_16x16x32_bf16(ka1, qf1, s, 0, 0, 0);
  }
  if (njt > 2) {
    kreg = *(const bf16x8*)(kg0 + (size_t)(128 + jr) * BATCH * PJP);
    vreg = *(const bf16x8*)(vg0 + 128);
  }

  for (int jt = 0; jt < njt; ++jt) {
    if (jt) __syncthreads();         // publish buf[(jt+1)%3]; WAR-guard buf[(jt+2)%3]
    if (jt + 2 < njt) {              // write tile jt+2 (regs loaded one iter ago)
      *(bf16x8*)(Ks[(jt + 2) % 3] + lds_off) = kreg;
      *(bf16x8*)(Vs[(jt + 2) % 3] + lds_off) = vreg;
    }
    if (jt + 3 < njt) {              // prefetch tile jt+3 into regs
      int j0n = (jt + 3) * 64;
      kreg = *(const bf16x8*)(kg0 + (size_t)(j0n + jr) * BATCH * PJP);
      vreg = *(const bf16x8*)(vg0 + j0n);
    }

    // QK(jt+1) issued BEFORE the exp of tile jt (independent -> interleave)
    f32x4 stN[4];
    bool more = (jt + 1 < njt);
    if (more) {
      const bf16_t* ks = Ks[(jt + 1) % 3];
      #pragma unroll
      for (int mt = 0; mt < 4; ++mt) {
        const bf16_t* kr = ks + (mt * 16 + c) * 64;
        bf16x8 ka0 = *(const bf16x8*)(kr + ((quad) ^ c7) * 8);
        bf16x8 ka1 = *(const bf16x8*)(kr + ((quad + 4) ^ c7) * 8);
        f32x4 s = {};
        s = __builtin_amdgcn_mfma_f32_16x16x32_bf16(ka0, qf0, s, 0, 0, 0);
        stN[mt] = __builtin_amdgcn_mfma_f32_16x16x32_bf16(ka1, qf1, s, 0, 0, 0);
      }
    }

    // ---- softmax finish of tile jt (VALU, overlaps QK above) ----
    if (jt >= 2 * qb) {
      int j0 = jt * 64;
      int ig = i0 + wave * 16 + c;
      #pragma unroll
      for (int mt = 0; mt < 4; ++mt)
        #pragma unroll
        for (int r = 0; r < 4; ++r)
          if (j0 + mt * 16 + quad * 4 + r > ig) st[mt][r] = -1e30f;
    }
    #pragma unroll
    for (int mt = 0; mt < 4; ++mt)
      #pragma unroll
      for (int r = 0; r < 4; ++r) {
        st[mt][r] = EXP2F(st[mt][r]);
        lrow += st[mt][r];
      }

    bf16_t* pw = Ps[wave];
    #pragma unroll
    for (int mt = 0; mt < 4; ++mt) {
      bf16x4 pv;
      #pragma unroll
      for (int r = 0; r < 4; ++r) pv[r] = (bf16_t)st[mt][r];
      int joct = mt * 2 + (quad >> 1);
      *(bf16x4*)(pw + c * 64 + (joct ^ c7) * 8 + (quad & 1) * 4) = pv;
    }
    const bf16_t* pr = pw + c * 64;
    bf16x8 pa0 = *(const bf16x8*)(pr + ((quad) ^ c7) * 8);
    bf16x8 pa1 = *(const bf16x8*)(pr + ((quad + 4) ^ c7) * 8);

    const bf16_t* vs = Vs[jt % 3];
    #pragma unroll
    for (int nt = 0; nt < 4; ++nt) {
      const bf16_t* vr = vs + (nt * 16 + c) * 64;
      bf16x8 vb0 = *(const bf16x8*)(vr + ((quad) ^ c7) * 8);
      bf16x8 vb1 = *(const bf16x8*)(vr + ((quad + 4) ^ c7) * 8);
      o[nt] = __builtin_amdgcn_mfma_f32_16x16x32_bf16(vb0, pa0, o[nt], 0, 0, 0);
      o[nt] = __builtin_amdgcn_mfma_f32_16x16x32_bf16(vb1, pa1, o[nt], 0, 0, 0);
    }

    if (more) {
      #pragma unroll
      for (int mt = 0; mt < 4; ++mt) st[mt] = stN[mt];
    }
  }

  float lfull = lrow;
  lfull += __shfl_xor(lfull, 16);
  lfull += __shfl_xor(lfull, 32);
  float linv = 1.0f / lfull;
  int orow = (i0 + wave * 16 + c) * BATCH + b;
  #pragma unroll
  for (int nt = 0; nt < 4; ++nt) {
    bf16x4 pv;
    #pragma unroll
    for (int r = 0; r < 4; ++r) pv[r] = (bf16_t)(o[nt][r] * linv);
    *(bf16x4*)(AO + (size_t)orow * HID + h * HDIM + nt * 16 + quad * 4) = pv;
  }
}

extern "C" void kernel_launch(void* const* d_in, const int* in_sizes, int n_in,
                              void* d_out, int out_size, void* d_ws, size_t ws_size,
                              hipStream_t stream) {
  const float* x      = (const float*)d_in[0];   // [2048][2][1024]
  const float* W_proj = (const float*)d_in[1];   // [1024][3072]
  const float* b_proj = (const float*)d_in[2];   // [3072]
  const float* W_out  = (const float*)d_in[3];   // [1024][1024]
  const float* b_out  = (const float*)d_in[4];   // [1024]

  bf16_t* Xb  = (bf16_t*)d_ws;                               // 4096*1024
  bf16_t* Wpt = Xb  + (size_t)NBROW * EMB;                   // 3072*1024
  bf16_t* Wot = Wpt + (size_t)3 * HID * EMB;                 // 1024*1024
  bf16_t* Pj  = Wot + (size_t)HID * EMB;                     // 4096*3072
  bf16_t* AO  = Pj  + (size_t)NBROW * 3 * HID;               // 4096*1024
  bf16_t* Vt  = AO  + (size_t)NBROW * HID;                   // 32*64*2048

  prep_kernel<<<8192, 256, 0, stream>>>(x, W_proj, W_out, Xb, Wpt, Wot);
  gemm_bt_kernel<128, 128, true, true, true>
      <<<dim3(NBROW / 128, 3 * HID / 128), 256, 0, stream>>>(
      Xb, Wpt, b_proj, (void*)Pj, Vt, NBROW, 3 * HID, EMB);
  flash_attn_kernel<<<512, 512, 0, stream>>>(Pj, Vt, AO);
  // out-projection: BN=64 -> 512 blocks (2-3 blocks/CU, latency-bound fix)
  gemm_bt_kernel<128, 64, false, false, false>
      <<<dim3(NBROW / 128, EMB / 64), 256, 0, stream>>>(
      AO, Wot, b_out, d_out, nullptr, NBROW, EMB, HID);
}